// Round 1
// baseline (2499.805 us; speedup 1.0000x reference)
//
#include <hip/hip_runtime.h>
#include <float.h>
#include <math.h>

#define DIM   512
#define KCB   1024
#define TM    32      // rows per block
#define DC    32      // d-chunk staged per stage
#define KT    512     // codebook entries per k-tile
#define CS_LD (KT + 1)

// ---------------- codebook norms ----------------
__global__ __launch_bounds__(64) void cnorm_kernel(const float* __restrict__ cb,
                                                   float* __restrict__ cnorm) {
    int k = blockIdx.x;
    const float4* row = (const float4*)(cb + (size_t)k * DIM);
    float s = 0.f;
    for (int i = threadIdx.x; i < DIM / 4; i += 64) {
        float4 v = row[i];
        s += v.x * v.x + v.y * v.y + v.z * v.z + v.w * v.w;
    }
#pragma unroll
    for (int off = 32; off > 0; off >>= 1) s += __shfl_xor(s, off);
    if (threadIdx.x == 0) cnorm[k] = s;
}

// ---------------- main: scores + argmin + fused epilogue ----------------
__global__ __launch_bounds__(256) void vq_main(
    const float* __restrict__ X, const float* __restrict__ CB,
    const float* __restrict__ cnorm, float* __restrict__ out,
    int* __restrict__ hist, float* __restrict__ loss_acc) {
    extern __shared__ char smem_raw[];
    float* Xs = (float*)smem_raw;                 // [TM][DIM]         16384 f
    float* Cs = Xs + TM * DIM;                    // [DC][KT+1]        16416 f
    int*   bestIdxSm = (int*)(Cs + DC * CS_LD);   // [TM]
    float* wsumSm = (float*)(bestIdxSm + TM);     // [4]

    const int t = threadIdx.x;
    const int rowbase = blockIdx.x * TM;

    // stage X tile (fp32, resident whole kernel)
    const float4* Xg = (const float4*)(X + (size_t)rowbase * DIM);
#pragma unroll
    for (int i = 0; i < (TM * DIM / 4) / 256; ++i) {  // 16 iters
        int idx = t + i * 256;
        int m = idx >> 7;          // 128 float4 per row
        int d4 = idx & 127;
        float4 v = Xg[idx];
        *(float4*)&Xs[m * DIM + d4 * 4] = v;
    }

    const int kc_sub = t & 63;   // lane within wave
    const int mg = t >> 6;       // wave id -> row group (8 rows)

    float bestS[8];
    int bestI[8];
#pragma unroll
    for (int r = 0; r < 8; ++r) { bestS[r] = FLT_MAX; bestI[r] = 0; }

    const float4* CBg4 = (const float4*)CB;

    for (int kt = 0; kt < KCB / KT; ++kt) {
        float acc[8][8];
#pragma unroll
        for (int c = 0; c < 8; ++c)
#pragma unroll
            for (int r = 0; r < 8; ++r) acc[c][r] = 0.f;

        for (int dc = 0; dc < DIM; dc += DC) {
            __syncthreads();  // protect Cs from previous stage's readers
            // stage Cs transposed: Cs[d][kc] = CB[kt*KT+kc][dc+d]
#pragma unroll
            for (int i = 0; i < (KT * DC / 4) / 256; ++i) {  // 16 iters
                int l = t + i * 256;
                int kc = l >> 3;     // 8 float4 per (row, d-chunk)
                int j4 = l & 7;
                float4 v = CBg4[(size_t)(kt * KT + kc) * (DIM / 4) + (dc >> 2) + j4];
                Cs[(j4 * 4 + 0) * CS_LD + kc] = v.x;
                Cs[(j4 * 4 + 1) * CS_LD + kc] = v.y;
                Cs[(j4 * 4 + 2) * CS_LD + kc] = v.z;
                Cs[(j4 * 4 + 3) * CS_LD + kc] = v.w;
            }
            __syncthreads();
            // compute: 8 rows x 8 cols register tile per thread
            for (int d4 = 0; d4 < DC; d4 += 4) {
                float4 xa[8];
#pragma unroll
                for (int r = 0; r < 8; ++r)
                    xa[r] = *(const float4*)&Xs[(mg * 8 + r) * DIM + dc + d4];
#pragma unroll
                for (int c = 0; c < 8; ++c) {
                    int kcol = kc_sub + c * 64;
                    float c0 = Cs[(d4 + 0) * CS_LD + kcol];
                    float c1 = Cs[(d4 + 1) * CS_LD + kcol];
                    float c2 = Cs[(d4 + 2) * CS_LD + kcol];
                    float c3 = Cs[(d4 + 3) * CS_LD + kcol];
#pragma unroll
                    for (int r = 0; r < 8; ++r) {
                        acc[c][r] = fmaf(xa[r].x, c0, acc[c][r]);
                        acc[c][r] = fmaf(xa[r].y, c1, acc[c][r]);
                        acc[c][r] = fmaf(xa[r].z, c2, acc[c][r]);
                        acc[c][r] = fmaf(xa[r].w, c3, acc[c][r]);
                    }
                }
            }
        }
        // fold this k-tile into per-lane running best
#pragma unroll
        for (int c = 0; c < 8; ++c) {
            int kc = kt * KT + kc_sub + c * 64;
            float cn = cnorm[kc];
#pragma unroll
            for (int r = 0; r < 8; ++r) {
                float s = fmaf(-2.f, acc[c][r], cn);
                if (s < bestS[r]) { bestS[r] = s; bestI[r] = kc; }
            }
        }
    }

    // wave butterfly argmin (min score, lowest index on ties — matches jnp.argmin)
#pragma unroll
    for (int r = 0; r < 8; ++r) {
        float s = bestS[r];
        int bi = bestI[r];
#pragma unroll
        for (int off = 32; off > 0; off >>= 1) {
            float s2 = __shfl_xor(s, off);
            int i2 = __shfl_xor(bi, off);
            if (s2 < s || (s2 == s && i2 < bi)) { s = s2; bi = i2; }
        }
        if (kc_sub == 0) bestIdxSm[mg * 8 + r] = bi;
    }
    __syncthreads();

    if (t < TM) atomicAdd(&hist[bestIdxSm[t]], 1);

    // gather quantized rows, write output (scalar stores: d_out+1 breaks 16B align),
    // accumulate loss partial
    float lsum = 0.f;
    float* outq = out + 1;
    for (int m = 0; m < TM; ++m) {
        int bi = bestIdxSm[m];
        const float* crow = CB + (size_t)bi * DIM;
        float q0 = crow[t];
        float q1 = crow[t + 256];
        float x0 = Xs[m * DIM + t];
        float x1 = Xs[m * DIM + t + 256];
        size_t base = (size_t)(rowbase + m) * DIM;
        outq[base + t] = q0;
        outq[base + t + 256] = q1;
        float d0 = q0 - x0, d1 = q1 - x1;
        lsum += d0 * d0 + d1 * d1;
    }
#pragma unroll
    for (int off = 32; off > 0; off >>= 1) lsum += __shfl_xor(lsum, off);
    if ((t & 63) == 0) wsumSm[t >> 6] = lsum;
    __syncthreads();
    if (t == 0) {
        atomicAdd(loss_acc, wsumSm[0] + wsumSm[1] + wsumSm[2] + wsumSm[3]);
    }
}

// ---------------- finalize: loss scalar + perplexity ----------------
__global__ __launch_bounds__(256) void finalize_kernel(
    const int* __restrict__ hist, const float* __restrict__ loss_acc,
    float* __restrict__ out, int n_rows, int q_count) {
    __shared__ float wsum[4];
    int t = threadIdx.x;
    float invN = 1.f / (float)n_rows;
    float h = 0.f;
    for (int k = t; k < KCB; k += 256) {
        float p = (float)hist[k] * invN;
        h += p * logf(p + 1e-10f);
    }
#pragma unroll
    for (int off = 32; off > 0; off >>= 1) h += __shfl_xor(h, off);
    if ((t & 63) == 0) wsum[t >> 6] = h;
    __syncthreads();
    if (t == 0) {
        float H = -(wsum[0] + wsum[1] + wsum[2] + wsum[3]);
        out[0] = loss_acc[0] * (1.25f / (float)q_count);  // q + 0.25*e, both == mean((q-x)^2)
        out[1 + q_count] = expf(H);
    }
}

extern "C" void kernel_launch(void* const* d_in, const int* in_sizes, int n_in,
                              void* d_out, int out_size, void* d_ws, size_t ws_size,
                              hipStream_t stream) {
    const float* X = (const float*)d_in[0];
    const float* CB = (const float*)d_in[1];
    float* out = (float*)d_out;
    int N = in_sizes[0] / DIM;  // 65536 rows

    // ws layout: [0,4K) cnorm | [4K,8K) hist | [8K, +64) loss accumulator
    float* cnorm = (float*)d_ws;
    int* hist = (int*)((char*)d_ws + 4096);
    float* loss_acc = (float*)((char*)d_ws + 8192);

    hipMemsetAsync((char*)d_ws + 4096, 0, 4096 + 64, stream);
    cnorm_kernel<<<KCB, 64, 0, stream>>>(CB, cnorm);

    size_t smem_bytes = (size_t)(TM * DIM + DC * CS_LD) * sizeof(float)
                      + TM * sizeof(int) + 4 * sizeof(float);
    vq_main<<<N / TM, 256, smem_bytes, stream>>>(X, CB, cnorm, out, hist, loss_acc);

    finalize_kernel<<<1, 256, 0, stream>>>(hist, loss_acc, out, N, N * DIM);
}

// Round 2
// 431.127 us; speedup vs baseline: 5.7983x; 5.7983x over previous
//
#include <hip/hip_runtime.h>
#include <float.h>
#include <math.h>

#define DIM 512
#define KCB 1024
#define BM 64
#define DC 64
#define NCHUNK (DIM / DC)   // 8
#define THREADS 512
// ws layout (bytes)
#define CBT_OFF   0u         // CB fp16, chunk-transposed [8][1024][64] = 1 MB
#define CNORM_OFF 1048576u   // 4 KB
#define XNORM_OFF 1052672u   // 256 KB
#define HIST_OFF  1314816u   // 4 KB
#define LOSS_OFF  1318912u   // 64 B
#define XO 16                // byte offset of Xfp16 region inside d_out

typedef _Float16 half8 __attribute__((ext_vector_type(8)));
typedef float floatx4 __attribute__((ext_vector_type(4)));

// ---------- pre-pass: X fp32 -> fp16 (into d_out row slots) + xnorm ----------
__global__ __launch_bounds__(256) void prep_x(const float* __restrict__ X,
                                              char* __restrict__ ob,
                                              float* __restrict__ xnorm) {
    const int lane = threadIdx.x & 63;
    const int r = blockIdx.x * 4 + (threadIdx.x >> 6);
    const float4* src = (const float4*)(X + (size_t)r * DIM);
    float4 v0 = src[lane * 2];
    float4 v1 = src[lane * 2 + 1];
    half8 h;
    h[0] = (_Float16)v0.x; h[1] = (_Float16)v0.y; h[2] = (_Float16)v0.z; h[3] = (_Float16)v0.w;
    h[4] = (_Float16)v1.x; h[5] = (_Float16)v1.y; h[6] = (_Float16)v1.z; h[7] = (_Float16)v1.w;
    *(half8*)(ob + XO + (size_t)r * 2048 + lane * 16) = h;
    float s = v0.x * v0.x + v0.y * v0.y + v0.z * v0.z + v0.w * v0.w
            + v1.x * v1.x + v1.y * v1.y + v1.z * v1.z + v1.w * v1.w;
#pragma unroll
    for (int off = 32; off > 0; off >>= 1) s += __shfl_xor(s, off);
    if (lane == 0) xnorm[r] = s;
}

// ---------- pre-pass: CB fp32 -> fp16 chunk-transposed + cnorm ----------
__global__ __launch_bounds__(256) void prep_cb(const float* __restrict__ CB,
                                               char* __restrict__ ws) {
    const int lane = threadIdx.x & 63;
    const int k = blockIdx.x * 4 + (threadIdx.x >> 6);
    const float4* src = (const float4*)(CB + (size_t)k * DIM);
    float4 v0 = src[lane * 2];
    float4 v1 = src[lane * 2 + 1];
    half8 h;
    h[0] = (_Float16)v0.x; h[1] = (_Float16)v0.y; h[2] = (_Float16)v0.z; h[3] = (_Float16)v0.w;
    h[4] = (_Float16)v1.x; h[5] = (_Float16)v1.y; h[6] = (_Float16)v1.z; h[7] = (_Float16)v1.w;
    const int dc = lane >> 3, j = lane & 7;  // lane covers d = lane*8..lane*8+7
    *(half8*)(ws + CBT_OFF + (size_t)dc * 131072 + (size_t)k * 128 + j * 16) = h;
    float s = v0.x * v0.x + v0.y * v0.y + v0.z * v0.z + v0.w * v0.w
            + v1.x * v1.x + v1.y * v1.y + v1.z * v1.z + v1.w * v1.w;
#pragma unroll
    for (int off = 32; off > 0; off >>= 1) s += __shfl_xor(s, off);
    if (lane == 0) ((float*)(ws + CNORM_OFF))[k] = s;
}

// ---------- main: fp16 MFMA scores + fused argmin + epilogue ----------
__global__ __launch_bounds__(THREADS) void vq_main(
    char* __restrict__ ob, const float* __restrict__ CB32,
    const char* __restrict__ ws, int* __restrict__ hist,
    float* __restrict__ loss_acc) {
    extern __shared__ char smem[];
    char* CBs = smem;                       // [1024][64+8 fp16] stride 144 B
    char* Xs  = smem + (size_t)KCB * 144;   // [64][64+8 fp16]  stride 144 B
    // overlay on Xs after GEMM:
    float* argS = (float*)Xs;               // [8][64]
    int*   argI = (int*)(Xs + 2048);        // [8][64]
    int*   idxF = (int*)(Xs + 4096);        // [64]

    const int t = threadIdx.x;
    const int w = t >> 6;
    const int lane = t & 63;
    const int q = lane >> 4;
    const int ln = lane & 15;
    const int rowbase = blockIdx.x * BM;
    const float* cnorm = (const float*)(ws + CNORM_OFF);
    const float* xnorm = (const float*)(ws + XNORM_OFF);
    const char* cbT = ws + CBT_OFF;

    floatx4 acc[4][8];
#pragma unroll
    for (int ar = 0; ar < 4; ++ar)
#pragma unroll
        for (int bc = 0; bc < 8; ++bc) acc[ar][bc] = (floatx4){0.f, 0.f, 0.f, 0.f};

    const int xn = t >> 3, xj = t & 7;

    for (int dc = 0; dc < NCHUNK; ++dc) {
        __syncthreads();  // protect LDS from previous chunk's readers
        // stage X chunk: [64 rows][64 d] fp16, one 16B per thread
        float4 xv = *(const float4*)(ob + XO + (size_t)(rowbase + xn) * 2048 + dc * 128 + xj * 16);
        *(float4*)(Xs + xn * 144 + xj * 16) = xv;
        // stage CB chunk: [1024 rows][64 d] fp16 (contiguous 128 KB in cbT)
#pragma unroll
        for (int i = 0; i < 16; ++i) {
            int e = i * THREADS + t;
            float4 cv = *(const float4*)(cbT + (size_t)dc * 131072 + (size_t)e * 16);
            *(float4*)(CBs + (e >> 3) * 144 + (e & 7) * 16) = cv;
        }
        __syncthreads();
#pragma unroll
        for (int ks = 0; ks < 2; ++ks) {
            half8 a[4];
#pragma unroll
            for (int ar = 0; ar < 4; ++ar)
                a[ar] = *(const half8*)(Xs + (ar * 16 + ln) * 144 + ks * 64 + q * 16);
#pragma unroll
            for (int bc = 0; bc < 8; ++bc) {
                half8 b = *(const half8*)(CBs + (w * 128 + bc * 16 + ln) * 144 + ks * 64 + q * 16);
#pragma unroll
                for (int ar = 0; ar < 4; ++ar)
                    acc[ar][bc] = __builtin_amdgcn_mfma_f32_16x16x32_f16(a[ar], b, acc[ar][bc], 0, 0, 0);
            }
        }
    }

    // fold scores into per-lane running best (16 rows/lane, ascending cols)
    float bestS[16];
    int bestI[16];
#pragma unroll
    for (int li = 0; li < 16; ++li) { bestS[li] = 3.0e38f; bestI[li] = 0; }
#pragma unroll
    for (int bc = 0; bc < 8; ++bc) {
        int col = w * 128 + bc * 16 + ln;
        float cn = cnorm[col];
#pragma unroll
        for (int ar = 0; ar < 4; ++ar)
#pragma unroll
            for (int r = 0; r < 4; ++r) {
                float s = fmaf(-2.f, acc[ar][bc][r], cn);
                int li = ar * 4 + r;
                if (s < bestS[li]) { bestS[li] = s; bestI[li] = col; }
            }
    }
    // butterfly across the 16 lanes holding the same rows (lowest index wins ties)
#pragma unroll
    for (int off = 1; off <= 8; off <<= 1) {
#pragma unroll
        for (int li = 0; li < 16; ++li) {
            float s2 = __shfl_xor(bestS[li], off);
            int i2 = __shfl_xor(bestI[li], off);
            if (s2 < bestS[li] || (s2 == bestS[li] && i2 < bestI[li])) {
                bestS[li] = s2; bestI[li] = i2;
            }
        }
    }
    __syncthreads();  // all Xs reads done before overlay writes
    if (ln == 0) {
#pragma unroll
        for (int li = 0; li < 16; ++li) {
            int row = (li >> 2) * 16 + q * 4 + (li & 3);
            argS[w * 64 + row] = bestS[li];
            argI[w * 64 + row] = bestI[li];
        }
    }
    __syncthreads();
    if (t < BM) {
        float s = argS[t];
        int bi = argI[t];
#pragma unroll
        for (int ww = 1; ww < 8; ++ww) {  // ascending wave = ascending cols: first-occurrence kept
            float s2 = argS[ww * 64 + t];
            int i2 = argI[ww * 64 + t];
            if (s2 < s || (s2 == s && i2 < bi)) { s = s2; bi = i2; }
        }
        idxF[t] = bi;
        atomicAdd(&hist[bi], 1);
        float l = s + xnorm[rowbase + t];  // = ||x - c_best||^2
#pragma unroll
        for (int off = 32; off > 0; off >>= 1) l += __shfl_xor(l, off);
        if (t == 0) atomicAdd(loss_acc, l);
    }
    __syncthreads();
    // gather + write quantized (overwrites this block's own Xfp16 rows only)
    float* outq = (float*)ob;
    for (int m = 0; m < BM; ++m) {
        int bi = idxF[m];
        float qv = CB32[(size_t)bi * DIM + t];
        outq[1 + (size_t)(rowbase + m) * DIM + t] = qv;
    }
}

// ---------- finalize: loss scalar + perplexity ----------
__global__ __launch_bounds__(256) void finalize_kernel(
    const int* __restrict__ hist, const float* __restrict__ loss_acc,
    float* __restrict__ out, int n_rows, int q_count) {
    __shared__ float wsum[4];
    int t = threadIdx.x;
    float invN = 1.f / (float)n_rows;
    float h = 0.f;
    for (int k = t; k < KCB; k += 256) {
        float p = (float)hist[k] * invN;
        h += p * logf(p + 1e-10f);
    }
#pragma unroll
    for (int off = 32; off > 0; off >>= 1) h += __shfl_xor(h, off);
    if ((t & 63) == 0) wsum[t >> 6] = h;
    __syncthreads();
    if (t == 0) {
        float H = -(wsum[0] + wsum[1] + wsum[2] + wsum[3]);
        out[0] = loss_acc[0] * (1.25f / (float)q_count);
        out[1 + q_count] = expf(H);
    }
}

extern "C" void kernel_launch(void* const* d_in, const int* in_sizes, int n_in,
                              void* d_out, int out_size, void* d_ws, size_t ws_size,
                              hipStream_t stream) {
    const float* X = (const float*)d_in[0];
    const float* CB = (const float*)d_in[1];
    char* ob = (char*)d_out;
    char* ws = (char*)d_ws;
    int N = in_sizes[0] / DIM;  // 65536 rows

    hipMemsetAsync(ws + HIST_OFF, 0, 4096 + 64, stream);
    prep_cb<<<KCB / 4, 256, 0, stream>>>(CB, ws);
    prep_x<<<N / 4, 256, 0, stream>>>(X, ob, (float*)(ws + XNORM_OFF));

    size_t smem = (size_t)KCB * 144 + (size_t)BM * 144;  // 156672 B
    vq_main<<<N / BM, THREADS, smem, stream>>>(ob, CB, ws,
                                               (int*)(ws + HIST_OFF),
                                               (float*)(ws + LOSS_OFF));
    finalize_kernel<<<1, 256, 0, stream>>>((int*)(ws + HIST_OFF),
                                           (float*)(ws + LOSS_OFF),
                                           (float*)d_out, N, N * DIM);
}

// Round 3
// 375.315 us; speedup vs baseline: 6.6606x; 1.1487x over previous
//
#include <hip/hip_runtime.h>
#include <math.h>

#define DIM 512
#define KCB 1024
#define BM  64
#define NCH 8            // 8 d-chunks of 64
// ws layout (bytes)
#define CBT_OFF   0u         // CB fp16 pre-swizzled: [2 halves][8 chunks][4096 slots*16B] = 1 MB
#define CNORM_OFF 1048576u   // 4 KB
#define XNORM_OFF 1052672u   // 256 KB
#define HIST_OFF  1314816u   // 4 KB
#define LOSS_OFF  1318912u   // 64 B
#define XO 16                // X fp16 region offset inside d_out (block-owned slabs)

typedef _Float16 half8 __attribute__((ext_vector_type(8)));
typedef float floatx4 __attribute__((ext_vector_type(4)));

// async global->LDS DMA, 16B/lane; LDS dest = wave-uniform base + lane*16
__device__ __forceinline__ void g2l16(const void* g, void* l) {
    __builtin_amdgcn_global_load_lds(
        (const __attribute__((address_space(1))) unsigned int*)g,
        (__attribute__((address_space(3))) unsigned int*)l, 16, 0, 0);
}

// Swizzle: 16B group g of row r stored at p = g ^ (r&7); row stride 128 B.
// Read lane (ln,q): p = (ks*4+q) ^ (ln&7): lanes 0..7 distinct banks, 8..15 repeat
// -> 2-way aliasing = free (m136). Linear slot order = DMA-compatible (no padding).

// ---------------- merged prep: X->fp16 swizzled + xnorm | CB->fp16 swizzled + cnorm ----------------
__global__ __launch_bounds__(256) void prep(const float* __restrict__ X,
                                            const float* __restrict__ CB,
                                            char* __restrict__ ob,
                                            char* __restrict__ ws) {
    const int t = threadIdx.x;
    const int w = t >> 6, lane = t & 63;
    const int dc = lane >> 3, g = lane & 7;  // lane covers d = lane*8 .. +7
    const int b = blockIdx.x;
    if (b < 2048) {
        // X: 32 rows per block, 8 per wave
        for (int it = 0; it < 8; ++it) {
            int r = b * 32 + w * 8 + it;
            const float4* src = (const float4*)(X + (size_t)r * DIM);
            float4 v0 = src[lane * 2];
            float4 v1 = src[lane * 2 + 1];
            half8 hh;
            hh[0] = (_Float16)v0.x; hh[1] = (_Float16)v0.y; hh[2] = (_Float16)v0.z; hh[3] = (_Float16)v0.w;
            hh[4] = (_Float16)v1.x; hh[5] = (_Float16)v1.y; hh[6] = (_Float16)v1.z; hh[7] = (_Float16)v1.w;
            int rl = r & 63;
            int slot = rl * 8 + (g ^ (rl & 7));
            *(half8*)(ob + XO + (size_t)(r >> 6) * 131072 + dc * 8192 + slot * 16) = hh;
            float s = v0.x * v0.x + v0.y * v0.y + v0.z * v0.z + v0.w * v0.w
                    + v1.x * v1.x + v1.y * v1.y + v1.z * v1.z + v1.w * v1.w;
#pragma unroll
            for (int off = 32; off > 0; off >>= 1) s += __shfl_xor(s, off);
            if (lane == 0) ((float*)(ws + XNORM_OFF))[r] = s;
        }
    } else {
        int k = (b - 2048) * 4 + w;  // one code per wave
        const float4* src = (const float4*)(CB + (size_t)k * DIM);
        float4 v0 = src[lane * 2];
        float4 v1 = src[lane * 2 + 1];
        half8 hh;
        hh[0] = (_Float16)v0.x; hh[1] = (_Float16)v0.y; hh[2] = (_Float16)v0.z; hh[3] = (_Float16)v0.w;
        hh[4] = (_Float16)v1.x; hh[5] = (_Float16)v1.y; hh[6] = (_Float16)v1.z; hh[7] = (_Float16)v1.w;
        int h = k >> 9, kl = k & 511;
        int slot = kl * 8 + (g ^ (kl & 7));
        *(half8*)(ws + CBT_OFF + (size_t)h * 524288 + dc * 65536 + slot * 16) = hh;
        float s = v0.x * v0.x + v0.y * v0.y + v0.z * v0.z + v0.w * v0.w
                + v1.x * v1.x + v1.y * v1.y + v1.z * v1.z + v1.w * v1.w;
#pragma unroll
        for (int off = 32; off > 0; off >>= 1) s += __shfl_xor(s, off);
        if (lane == 0) ((float*)(ws + CNORM_OFF))[k] = s;
    }
}

// ---------------- main: fp16 MFMA scores (two 512-code halves) + fused argmin/epilogue ----------------
__global__ __launch_bounds__(256, 2) void vq_main(
    char* __restrict__ ob, const float* __restrict__ CB32,
    const char* __restrict__ ws, int* __restrict__ hist,
    float* __restrict__ loss_acc) {
    extern __shared__ char smem[];
    char* CBs = smem;            // [512 codes][64 halves] swizzled, 64 KB
    char* Xs  = smem + 65536;    // [64 rows][64 halves]  swizzled,  8 KB
    // epilogue overlay (after final sync):
    float* argS = (float*)smem;           // [4][64]
    int*   argI = (int*)(smem + 1024);    // [4][64]
    int*   idxF = (int*)(smem + 2048);    // [64]

    const int t = threadIdx.x;
    const int lane = t & 63;
    const int wu = __builtin_amdgcn_readfirstlane(t >> 6);  // wave id (scalar)
    const int q = lane >> 4, ln = lane & 15;
    const int pg = ln & 7;
    const int rb = blockIdx.x;
    const int rowbase = rb * BM;
    const float* cnorm = (const float*)(ws + CNORM_OFF);
    const float* xnorm = (const float*)(ws + XNORM_OFF);

    float bestS[16];
    int bestI[16];
#pragma unroll
    for (int li = 0; li < 16; ++li) { bestS[li] = 3.0e38f; bestI[li] = 0; }

    for (int h = 0; h < 2; ++h) {
        floatx4 acc[4][8];
#pragma unroll
        for (int ar = 0; ar < 4; ++ar)
#pragma unroll
            for (int bc = 0; bc < 8; ++bc) acc[ar][bc] = (floatx4){0.f, 0.f, 0.f, 0.f};

        for (int dc = 0; dc < NCH; ++dc) {
            __syncthreads();  // previous chunk's readers done
            // stage X chunk: 512 slots (2 DMA / wave)
#pragma unroll
            for (int i2 = 0; i2 < 2; ++i2) {
                int sb = (i2 * 4 + wu) * 64;
                g2l16(ob + XO + (size_t)rb * 131072 + dc * 8192 + (size_t)(sb + lane) * 16,
                      Xs + sb * 16);
            }
            // stage CB half-chunk: 4096 slots (16 DMA / wave)
#pragma unroll
            for (int i = 0; i < 16; ++i) {
                int sb = (i * 4 + wu) * 64;
                g2l16(ws + CBT_OFF + (size_t)h * 524288 + (size_t)dc * 65536 + (size_t)(sb + lane) * 16,
                      CBs + sb * 16);
            }
            __syncthreads();  // implicit vmcnt(0) drain
#pragma unroll
            for (int ks = 0; ks < 2; ++ks) {
                const int sw = ((ks << 2) | q) ^ pg;
                half8 a[4];
#pragma unroll
                for (int ar = 0; ar < 4; ++ar)
                    a[ar] = *(const half8*)(Xs + (ar * 16 + ln) * 128 + sw * 16);
#pragma unroll
                for (int bc = 0; bc < 8; ++bc) {
                    half8 bfr = *(const half8*)(CBs + (wu * 128 + bc * 16 + ln) * 128 + sw * 16);
#pragma unroll
                    for (int ar = 0; ar < 4; ++ar)
                        acc[ar][bc] = __builtin_amdgcn_mfma_f32_16x16x32_f16(a[ar], bfr, acc[ar][bc], 0, 0, 0);
                }
            }
        }
        // fold this half (ascending cols -> strict < keeps first occurrence)
#pragma unroll
        for (int bc = 0; bc < 8; ++bc) {
            int col = h * 512 + wu * 128 + bc * 16 + ln;
            float cn = cnorm[col];
#pragma unroll
            for (int ar = 0; ar < 4; ++ar)
#pragma unroll
                for (int r = 0; r < 4; ++r) {
                    float s = fmaf(-2.f, acc[ar][bc][r], cn);
                    int li = ar * 4 + r;
                    if (s < bestS[li]) { bestS[li] = s; bestI[li] = col; }
                }
        }
    }

    // butterfly across the 16 ln-lanes (lowest index wins ties)
#pragma unroll
    for (int off = 1; off <= 8; off <<= 1) {
#pragma unroll
        for (int li = 0; li < 16; ++li) {
            float s2 = __shfl_xor(bestS[li], off);
            int i2 = __shfl_xor(bestI[li], off);
            if (s2 < bestS[li] || (s2 == bestS[li] && i2 < bestI[li])) {
                bestS[li] = s2; bestI[li] = i2;
            }
        }
    }
    __syncthreads();  // all LDS frag reads done before overlay writes
    if (ln == 0) {
#pragma unroll
        for (int li = 0; li < 16; ++li) {
            int row = (li >> 2) * 16 + q * 4 + (li & 3);
            argS[wu * 64 + row] = bestS[li];
            argI[wu * 64 + row] = bestI[li];
        }
    }
    __syncthreads();
    if (t < BM) {  // exactly wave 0
        float s = argS[t];
        int bi = argI[t];
#pragma unroll
        for (int ww = 1; ww < 4; ++ww) {
            float s2 = argS[ww * 64 + t];
            int i2 = argI[ww * 64 + t];
            if (s2 < s || (s2 == s && i2 < bi)) { s = s2; bi = i2; }
        }
        idxF[t] = bi;
        atomicAdd(&hist[bi], 1);
        float l = s + xnorm[rowbase + t];  // ||x - c_best||^2
#pragma unroll
        for (int off = 32; off > 0; off >>= 1) l += __shfl_xor(l, off);
        if (t == 0) atomicAdd(loss_acc, l);
    }
    __syncthreads();
    // gather + write quantized (overwrites this block's own X-fp16 slab only)
    float* outq = (float*)ob + 1;
    for (int m = 0; m < BM; ++m) {
        int bi = idxF[m];
        const float* crow = CB32 + (size_t)bi * DIM;
        float v0 = crow[t];
        float v1 = crow[t + 256];
        size_t base = (size_t)(rowbase + m) * DIM;
        outq[base + t] = v0;
        outq[base + t + 256] = v1;
    }
}

// ---------------- finalize: loss scalar + perplexity ----------------
__global__ __launch_bounds__(256) void finalize_kernel(
    const int* __restrict__ hist, const float* __restrict__ loss_acc,
    float* __restrict__ out, int n_rows, int q_count) {
    __shared__ float wsum[4];
    int t = threadIdx.x;
    float invN = 1.f / (float)n_rows;
    float hsum = 0.f;
    for (int k = t; k < KCB; k += 256) {
        float p = (float)hist[k] * invN;
        hsum += p * logf(p + 1e-10f);
    }
#pragma unroll
    for (int off = 32; off > 0; off >>= 1) hsum += __shfl_xor(hsum, off);
    if ((t & 63) == 0) wsum[t >> 6] = hsum;
    __syncthreads();
    if (t == 0) {
        float H = -(wsum[0] + wsum[1] + wsum[2] + wsum[3]);
        out[0] = loss_acc[0] * (1.25f / (float)q_count);  // q_loss + 0.25*e_loss
        out[1 + q_count] = expf(H);
    }
}

extern "C" void kernel_launch(void* const* d_in, const int* in_sizes, int n_in,
                              void* d_out, int out_size, void* d_ws, size_t ws_size,
                              hipStream_t stream) {
    const float* X = (const float*)d_in[0];
    const float* CB = (const float*)d_in[1];
    char* ob = (char*)d_out;
    char* ws = (char*)d_ws;
    int N = in_sizes[0] / DIM;  // 65536 rows

    hipMemsetAsync(ws + HIST_OFF, 0, 4096 + 64, stream);
    prep<<<2048 + 256, 256, 0, stream>>>(X, CB, ob, ws);

    vq_main<<<N / BM, 256, 73728, stream>>>(ob, CB, ws,
                                            (int*)(ws + HIST_OFF),
                                            (float*)(ws + LOSS_OFF));
    finalize_kernel<<<1, 256, 0, stream>>>((int*)(ws + HIST_OFF),
                                           (float*)(ws + LOSS_OFF),
                                           (float*)d_out, N, N * DIM);
}